// Round 7
// baseline (407.041 us; speedup 1.0000x reference)
//
#include <hip/hip_runtime.h>

typedef unsigned short u16;
typedef __attribute__((ext_vector_type(4))) unsigned short u16x4;
typedef __attribute__((ext_vector_type(8))) unsigned short u16x8;
typedef __attribute__((ext_vector_type(4))) float f32x4;
typedef __attribute__((ext_vector_type(8))) __bf16 bf16x8;
typedef __attribute__((ext_vector_type(2))) unsigned int u32x2;
typedef __attribute__((ext_vector_type(4))) unsigned int u32x4;

// ---- workspace layout (bytes) ----
#define WS_XH    0UL          // CTXIB bf16 [8192][512]
#define WS_XT    8388608UL    // CTXTB bf16 [8192][512]
#define WS_W     16777216UL   // all weights bf16, contiguous (see prep_weights)
#define WS_BQI   24117248UL   // concat bias qkv_img fp32 [1536]
#define WS_BQT   24123392UL   // concat bias qkv_txt fp32 [1536]
#define WS_QKVI  24129536UL   // qkv_img bf16 [8192][1536] (V cols never written; Q pre-scaled)
#define WS_QKVT  49295360UL   // qkv_txt bf16
#define WS_VTI   74461184UL   // v_img^T bf16 [8*8*64][1024]  (written by GEMM epilogue)
#define WS_VTT   82849792UL   // v_txt^T
#define WS_CTXIA 91238400UL   // ctx img, img-key phase, bf16 [8192][512] (*0.5)
#define WS_CTXTA 99627008UL   // ctx txt, txt-key phase
#define WS_OCAT  108015616UL  // concat out bf16 [8192][1024]
// reuse of QKV_I/QKV_T region after attentions complete:
#define WS_OUT2  24129536UL   // out after w_cat bf16 [8192][512]
#define WS_QKVP  32518144UL   // pooled qkv bf16 [8192][1536]
#define WS_VTP   57683968UL   // v_pool^T
#define WS_CTXP  66072576UL   // ctx_pool bf16 [8192][512]

#define SCALE_LOG2E_O8 0.18033688011112042f  // log2(e)/8

__device__ __forceinline__ u16 f2bf(float f) {
  unsigned u = __float_as_uint(f);
  u += 0x7fffu + ((u >> 16) & 1u);   // RNE
  return (u16)(u >> 16);
}
__device__ __forceinline__ float bf2f(u16 v) {
  return __uint_as_float(((unsigned)v) << 16);
}
__device__ __forceinline__ bf16x8 as_bf(u16x8 v) { return __builtin_bit_cast(bf16x8, v); }
__device__ __forceinline__ f32x4 mfma16(bf16x8 a, bf16x8 b, f32x4 c) {
  return __builtin_amdgcn_mfma_f32_16x16x32_bf16(a, b, c, 0, 0, 0);
}
// pack two fp32 into one u32 of 2x bf16 in ONE VALU op (RNE)
__device__ __forceinline__ unsigned cvt_pk_bf16(float lo, float hi) {
  unsigned r;
  asm("v_cvt_pk_bf16_f32 %0, %1, %2" : "=v"(r) : "v"(lo), "v"(hi));
  return r;
}
// 8 fp32 -> bf16x8 in 4 VALU ops (RNE, numerically identical to f2bf path)
__device__ __forceinline__ u16x8 cvt8(float4 a, float4 b) {
  u32x4 pk;
  pk[0] = cvt_pk_bf16(a.x, a.y);
  pk[1] = cvt_pk_bf16(a.z, a.w);
  pk[2] = cvt_pk_bf16(b.x, b.y);
  pk[3] = cvt_pk_bf16(b.z, b.w);
  return __builtin_bit_cast(u16x8, pk);
}
// Raw barrier: lgkmcnt(0) (publish our ds_writes) + s_barrier, NO vmcnt drain.
// __syncthreads' implicit vmcnt(0) caps global-load prefetch distance at ONE compute
// phase (< HBM latency) -- this is the R6-diagnosed GEMM stall. Single asm with memory
// clobber so the compiler can't move LDS ops across it in either direction.
__device__ __forceinline__ void bar_novm() {
  asm volatile("s_waitcnt lgkmcnt(0)\n\ts_barrier" ::: "memory");
}

// ---------------- weight prep: convert+concat all weights / biases ----------------
__global__ __launch_bounds__(256) void prep_weights(
    const float* __restrict__ wqi, const float* __restrict__ wki, const float* __restrict__ wvi,
    const float* __restrict__ wqt, const float* __restrict__ wkt, const float* __restrict__ wvt,
    const float* __restrict__ woi, const float* __restrict__ wot,
    const float* __restrict__ wc,  const float* __restrict__ wip, const float* __restrict__ wop,
    const float* __restrict__ bqi, const float* __restrict__ bki, const float* __restrict__ bvi,
    const float* __restrict__ bqt, const float* __restrict__ bkt, const float* __restrict__ bvt,
    u16* __restrict__ wdst, float* __restrict__ bi, float* __restrict__ bt) {
  int i = blockIdx.x * 256 + threadIdx.x;
  if (i < 786432) {
    const float* s = i < 262144 ? wqi : (i < 524288 ? wki : wvi);
    wdst[i] = f2bf(s[i & 262143]);
  } else if (i < 1572864) {
    int j = i - 786432;
    const float* s = j < 262144 ? wqt : (j < 524288 ? wkt : wvt);
    wdst[i] = f2bf(s[j & 262143]);
  } else if (i < 1835008) wdst[i] = f2bf(woi[i - 1572864]);
  else if (i < 2097152)   wdst[i] = f2bf(wot[i - 1835008]);
  else if (i < 2621440)   wdst[i] = f2bf(wc [i - 2097152]);
  else if (i < 3407872)   wdst[i] = f2bf(wip[i - 2621440]);
  else if (i < 3670016)   wdst[i] = f2bf(wop[i - 3407872]);
  else if (i < 3671552) {
    int j = i - 3670016;
    bi[j] = j < 512 ? bqi[j] : (j < 1024 ? bki[j - 512] : bvi[j - 1024]);
  } else if (i < 3673088) {
    int j = i - 3671552;
    bt[j] = j < 512 ? bqt[j] : (j < 1024 ? bkt[j - 512] : bvt[j - 1024]);
  }
}

// ---------------- GEMM: C[M,N] = (A [+ A2])[M,K] @ W[N,K]^T + bias(f32) ----------------
// 128x128 tile, 4 waves (2x2 of 64x64), BK=32, double-buffered LDS.
// R7: 2-DEEP register pipeline + raw barrier (no vmcnt drain). R6 counters showed all
// GEMMs latency-bound (MfmaUtil 11.6, VALU 11.4, HBM 12%, 0 conflicts, 300 TF): the
// __syncthreads vmcnt(0) capped prefetch at 1 compute phase < HBM latency. Now TWO
// K-tiles live in named registers (explicit 2-step unroll -- no runtime-indexed reg
// arrays, they'd go to scratch); commit of tile i emits a COUNTED vmcnt leaving tile
// i+1's loads in flight across the barrier -> in-flight window = 2 phases >= HBM lat.
// Buffer-reuse safety: LDS buf b written at step s is re-written at s+2; every wave's
// reads of buf b (step s) are consumed by its MFMAs before it reaches the barrier of
// step s+1, which precedes the s+2 commit. One barrier per K-step. REQUIRES K % 64 == 0.
// af32: A is fp32, converted during staging via v_cvt_pk_bf16_f32 (no cvt kernels).
// A2 (nullable): elementwise bf16 add at staging. blockIdx.z==1 applies zd* deltas.
// vtout: V third of a QKV GEMM written TRANSPOSED. qcols/qscale: Q-column pre-scale.
__global__ __launch_bounds__(256) void gemm_bf16(
    const u16* __restrict__ A, const u16* __restrict__ A2, int lda, int af32,
    const u16* __restrict__ W,
    const float* __restrict__ bias, u16* __restrict__ C, int ldc, int coff, int K,
    int f32out, int qcols, float qscale, u16* __restrict__ vtout,
    long zdA, long zdA2, long zdW, long zdB, long zdC, long zdVT, int zdCoff) {
  if (blockIdx.z) {
    A += zdA;
    if (A2) A2 += zdA2;
    W += zdW; bias += zdB; C += zdC;
    if (vtout) vtout += zdVT;
    coff += zdCoff;
  }
  __shared__ __align__(16) u16 As[2][8 * 512];   // 8 KB per buffer
  __shared__ __align__(16) u16 Bs[2][8 * 512];
  const int tid = threadIdx.x, lane = tid & 63, wv = tid >> 6;
  const int wm = wv >> 1, wn = wv & 1;
  const int ln15 = lane & 15;
  const int m0 = blockIdx.x * 128, n0 = blockIdx.y * 128;

  const int srow = lane & 15, skc = lane >> 4;
  const u16* gW0 = W + (long)(n0 + wv * 32 + srow) * K + skc * 8;
  const u16* gW1 = gW0 + (long)16 * K;

  f32x4 acc[4][4];
#pragma unroll
  for (int j = 0; j < 4; ++j) {
    float bv = bias[n0 + wn * 64 + j * 16 + ln15];
#pragma unroll
    for (int i = 0; i < 4; ++i) acc[i][j] = f32x4{bv, bv, bv, bv};
  }

  // 16 MFMA on LDS buffer `b` (compile-time 0/1 at each call site)
  auto compute = [&](int b) __attribute__((always_inline)) {
    bf16x8 af[4], bfr[4];
#pragma unroll
    for (int i = 0; i < 4; ++i)
      af[i] = as_bf(*(const u16x8*)(As[b] + (wm * 4 + i) * 512 + lane * 8));
#pragma unroll
    for (int j = 0; j < 4; ++j)
      bfr[j] = as_bf(*(const u16x8*)(Bs[b] + (wn * 4 + j) * 512 + lane * 8));
#pragma unroll
    for (int i = 0; i < 4; ++i)
#pragma unroll
      for (int j = 0; j < 4; ++j) acc[i][j] = mfma16(af[i], bfr[j], acc[i][j]);
  };

  if (af32) {
    // ---- fp32-A staging (QKV GEMM reads hidden/text fp32 directly) ----
    const float* fA0 = (const float*)A + (long)(m0 + wv * 32 + srow) * lda + skc * 8;
    const float* fA1 = fA0 + (long)16 * lda;
    // two named register tile-sets (set0 = even K-steps, set1 = odd)
    float4 a00, a01, a02, a03, a10, a11, a12, a13;
    u16x8 b00, b01, b10, b11;
    a00 = *(const float4*)(fA0);      a01 = *(const float4*)(fA0 + 4);
    a02 = *(const float4*)(fA1);      a03 = *(const float4*)(fA1 + 4);
    b00 = *(const u16x8*)(gW0);       b01 = *(const u16x8*)(gW1);
    a10 = *(const float4*)(fA0 + 32); a11 = *(const float4*)(fA0 + 36);
    a12 = *(const float4*)(fA1 + 32); a13 = *(const float4*)(fA1 + 36);
    b10 = *(const u16x8*)(gW0 + 32);  b11 = *(const u16x8*)(gW1 + 32);
    for (int k0 = 0; k0 < K; k0 += 64) {
      { // step even: tile k0 -> buf 0, set 0
        u16* la = As[0] + wv * 1024;
        u16* lb = Bs[0] + wv * 1024;
        *(u16x8*)(la + lane * 8) = cvt8(a00, a01);        // counted vmcnt: set1 stays live
        *(u16x8*)(la + 512 + lane * 8) = cvt8(a02, a03);
        *(u16x8*)(lb + lane * 8) = b00;
        *(u16x8*)(lb + 512 + lane * 8) = b01;
        bar_novm();
        if (k0 + 64 < K) {
          a00 = *(const float4*)(fA0 + k0 + 64); a01 = *(const float4*)(fA0 + k0 + 68);
          a02 = *(const float4*)(fA1 + k0 + 64); a03 = *(const float4*)(fA1 + k0 + 68);
          b00 = *(const u16x8*)(gW0 + k0 + 64);  b01 = *(const u16x8*)(gW1 + k0 + 64);
        }
        compute(0);
      }
      { // step odd: tile k0+32 -> buf 1, set 1
        u16* la = As[1] + wv * 1024;
        u16* lb = Bs[1] + wv * 1024;
        *(u16x8*)(la + lane * 8) = cvt8(a10, a11);
        *(u16x8*)(la + 512 + lane * 8) = cvt8(a12, a13);
        *(u16x8*)(lb + lane * 8) = b10;
        *(u16x8*)(lb + 512 + lane * 8) = b11;
        bar_novm();
        if (k0 + 96 < K) {
          a10 = *(const float4*)(fA0 + k0 + 96); a11 = *(const float4*)(fA0 + k0 + 100);
          a12 = *(const float4*)(fA1 + k0 + 96); a13 = *(const float4*)(fA1 + k0 + 100);
          b10 = *(const u16x8*)(gW0 + k0 + 96);  b11 = *(const u16x8*)(gW1 + k0 + 96);
        }
        compute(1);
      }
    }
  } else {
    // ---- bf16-A staging (optional A2 elementwise add), same 2-deep structure ----
    const u16* gA0 = A + (long)(m0 + wv * 32 + srow) * lda + skc * 8;
    const u16* gA1 = gA0 + (long)16 * lda;
    const u16* gA20 = A2 + (long)(m0 + wv * 32 + srow) * lda + skc * 8;  // valid only if A2
    const u16* gA21 = gA20 + (long)16 * lda;
    u16x8 a00, a01, a10, a11, b00, b01, b10, b11, c00, c01, c10, c11;
    a00 = *(const u16x8*)(gA0);      a01 = *(const u16x8*)(gA1);
    b00 = *(const u16x8*)(gW0);      b01 = *(const u16x8*)(gW1);
    a10 = *(const u16x8*)(gA0 + 32); a11 = *(const u16x8*)(gA1 + 32);
    b10 = *(const u16x8*)(gW0 + 32); b11 = *(const u16x8*)(gW1 + 32);
    if (A2) {
      c00 = *(const u16x8*)(gA20);      c01 = *(const u16x8*)(gA21);
      c10 = *(const u16x8*)(gA20 + 32); c11 = *(const u16x8*)(gA21 + 32);
    }
    for (int k0 = 0; k0 < K; k0 += 64) {
      { // step even
        u16x8 wa0 = a00, wa1 = a01;
        if (A2) {
#pragma unroll
          for (int u = 0; u < 8; ++u) {
            wa0[u] = f2bf(bf2f(a00[u]) + bf2f(c00[u]));
            wa1[u] = f2bf(bf2f(a01[u]) + bf2f(c01[u]));
          }
        }
        u16* la = As[0] + wv * 1024;
        u16* lb = Bs[0] + wv * 1024;
        *(u16x8*)(la + lane * 8) = wa0;
        *(u16x8*)(la + 512 + lane * 8) = wa1;
        *(u16x8*)(lb + lane * 8) = b00;
        *(u16x8*)(lb + 512 + lane * 8) = b01;
        bar_novm();
        if (k0 + 64 < K) {
          a00 = *(const u16x8*)(gA0 + k0 + 64); a01 = *(const u16x8*)(gA1 + k0 + 64);
          b00 = *(const u16x8*)(gW0 + k0 + 64); b01 = *(const u16x8*)(gW1 + k0 + 64);
          if (A2) { c00 = *(const u16x8*)(gA20 + k0 + 64); c01 = *(const u16x8*)(gA21 + k0 + 64); }
        }
        compute(0);
      }
      { // step odd
        u16x8 wa0 = a10, wa1 = a11;
        if (A2) {
#pragma unroll
          for (int u = 0; u < 8; ++u) {
            wa0[u] = f2bf(bf2f(a10[u]) + bf2f(c10[u]));
            wa1[u] = f2bf(bf2f(a11[u]) + bf2f(c11[u]));
          }
        }
        u16* la = As[1] + wv * 1024;
        u16* lb = Bs[1] + wv * 1024;
        *(u16x8*)(la + lane * 8) = wa0;
        *(u16x8*)(la + 512 + lane * 8) = wa1;
        *(u16x8*)(lb + lane * 8) = b10;
        *(u16x8*)(lb + 512 + lane * 8) = b11;
        bar_novm();
        if (k0 + 96 < K) {
          a10 = *(const u16x8*)(gA0 + k0 + 96); a11 = *(const u16x8*)(gA1 + k0 + 96);
          b10 = *(const u16x8*)(gW0 + k0 + 96); b11 = *(const u16x8*)(gW1 + k0 + 96);
          if (A2) { c10 = *(const u16x8*)(gA20 + k0 + 96); c11 = *(const u16x8*)(gA21 + k0 + 96); }
        }
        compute(1);
      }
    }
  }
  // epilogue: C/D layout col=lane&15, row=quad*4+reg (m89/m91 verified)
  const int quad = lane >> 4;
  const int qr4 = quad * 4;
  if (vtout && n0 >= 1024) {
    // V tile -> transposed store into VT[(b*8+h)*64+d][l]
#pragma unroll
    for (int j = 0; j < 4; ++j) {
      int col = n0 + wn * 64 + j * 16 + ln15;    // 1024..1535
      int dg = col - 1024;
#pragma unroll
      for (int i = 0; i < 4; ++i) {
        int row0 = m0 + wm * 64 + i * 16 + qr4;  // 4 consecutive C-rows = 4 VT cols
        long vr = ((long)(row0 >> 10) * 8 + (dg >> 6)) * 64 + (dg & 63);
        u16x4 ov;
#pragma unroll
        for (int r = 0; r < 4; ++r) ov[r] = f2bf(acc[i][j][r]);
        *(u16x4*)(vtout + vr * 1024 + (row0 & 1023)) = ov;
      }
    }
    return;
  }
  float colsc[4];
#pragma unroll
  for (int j = 0; j < 4; ++j)
    colsc[j] = (n0 + wn * 64 + j * 16 < qcols) ? qscale : 1.0f;
#pragma unroll
  for (int i = 0; i < 4; ++i)
#pragma unroll
    for (int r = 0; r < 4; ++r) {
      int row = m0 + wm * 64 + i * 16 + qr4 + r;
      long cidx = (long)row * ldc + coff + n0 + wn * 64 + ln15;
      if (f32out) {
        float* cf = (float*)C + cidx;
#pragma unroll
        for (int j = 0; j < 4; ++j) cf[j * 16] = acc[i][j][r] * colsc[j];
      } else {
        u16* cp = C + cidx;
#pragma unroll
        for (int j = 0; j < 4; ++j) cp[j * 16] = f2bf(acc[i][j][r] * colsc[j]);
      }
    }
}

// ---------------- flash attention, S^T formulation: NO P LDS round-trip ----------------
// Compute S^T = K.Q^T (A=K-frag from Kt, B=Q-frag). S^T C-layout IS a PV B-fragment under
// the fixed key permutation slot(quad*8+j) <-> key (j<4 ? 4q+j : 16+4q+j-4): P packs
// entirely in registers. l = ones.P^T via 1 MFMA. No-max softmax (Q pre-scaled by log2e/8).
// NQF=2 is the measured sweet spot (R4). Issue-saturated (MFMA 40 + VALU 50) -- left as-is.
// __launch_bounds__ stays (256) with NO min-waves clause ((256,8) spills: r1, 19x).
template <int NQF, bool DUAL>
__global__ __launch_bounds__(256) void attn_flash(
    const u16* __restrict__ Q0, const u16* __restrict__ Q1, int ldq,
    const u16* __restrict__ K0, const u16* __restrict__ VT0,
    const u16* __restrict__ K1, const u16* __restrict__ VT1, int ldk,
    u16* __restrict__ O00, u16* __restrict__ O01,
    u16* __restrict__ O10, u16* __restrict__ O11, int ldo, float outscale) {
  __shared__ __align__(16) u16 Kt[2][32][72];   // K tile, natural key order [key][d]
  __shared__ __align__(16) u16 Vt[2][64][40];   // V^T tile, slot-permuted key order [d][slot]
  const int tid = threadIdx.x, lane = tid & 63, wv = tid >> 6;
  const int ln15 = lane & 15, quad = lane >> 4, q8 = quad * 8;
  const int h = blockIdx.y;

  const u16 *Q, *K, *VT;
  u16* O;
  int qtile, b;
  if constexpr (DUAL) {
    qtile = blockIdx.x >> 1;
    const int phase = blockIdx.x & 1;
    const int qsel = blockIdx.z & 1;
    b = blockIdx.z >> 1;
    Q = qsel ? Q1 : Q0;
    const int ksel = qsel ^ phase;   // 0: img keys, 1: txt keys
    K = ksel ? K1 : K0;
    VT = ksel ? VT1 : VT0;
    O = qsel ? (phase ? O11 : O10) : (phase ? O01 : O00);
  } else {
    qtile = blockIdx.x;
    b = blockIdx.z;
    Q = Q0; K = K0; VT = VT0; O = O00;
  }
  const long qrow = (long)b * 1024 + qtile * (NQF * 64) + wv * (NQF * 16);

  // Q fragments (serve as MFMA B operand: n=lane&15=q, k=quad*8+j=d) [qi][d-half]
  bf16x8 qf[NQF][2];
#pragma unroll
  for (int qi = 0; qi < NQF; ++qi) {
    const u16* qp = Q + (qrow + qi * 16 + ln15) * ldq + h * 64;
    qf[qi][0] = as_bf(*(const u16x8*)(qp + q8));
    qf[qi][1] = as_bf(*(const u16x8*)(qp + 32 + q8));
  }

  u16x8 ones_u;
#pragma unroll
  for (int j = 0; j < 8; ++j) ones_u[j] = 0x3F80;  // bf16 1.0
  const bf16x8 onesb = as_bf(ones_u);

  // staging thread->element maps
  const int kk = tid >> 3, dc = (tid & 7) * 8;        // K: natural rows
  const int vd = tid >> 2;                            // V: d-row
  const int ko = (tid & 3) * 8;                       // natural key offset (8 keys)
  const int vs0 = ((tid & 1) << 4) | ((tid & 2) << 1);// slot base: ko 0,8,16,24 -> 0,16,4,20
  const u16* Kbase = K + ((long)b * 1024 + kk) * ldk + h * 64 + dc;
  const u16* Vbase = VT + ((long)((b * 8 + h) * 64 + vd)) * 1024 + ko;

  f32x4 o[NQF][4];
  f32x4 lacc[NQF];
#pragma unroll
  for (int qi = 0; qi < NQF; ++qi) {
    lacc[qi] = f32x4{0.f, 0.f, 0.f, 0.f};
#pragma unroll
    for (int j = 0; j < 4; ++j) o[qi][j] = f32x4{0.f, 0.f, 0.f, 0.f};
  }

  // prefetch tile 0
  u32x4 kreg = *(const u32x4*)(Kbase);
  u32x4 vreg = *(const u32x4*)(Vbase);

  int cur = 0;
  for (int k0 = 0; k0 < 1024; k0 += 32, cur ^= 1) {
    // commit staged regs for THIS tile into buffer cur (waits the in-flight loads here)
    *(u32x4*)(&Kt[cur][kk][dc]) = kreg;
    u32x2 vlo = {vreg[0], vreg[1]}, vhi = {vreg[2], vreg[3]};
    *(u32x2*)(&Vt[cur][vd][vs0]) = vlo;
    *(u32x2*)(&Vt[cur][vd][vs0 + 8]) = vhi;
    __syncthreads();
    // issue next tile's global loads AFTER the barrier (so its vmcnt(0) doesn't drain them)
    if (k0 + 32 < 1024) {
      kreg = *(const u32x4*)(Kbase + (long)(k0 + 32) * ldk);
      vreg = *(const u32x4*)(Vbase + (k0 + 32));
    }

    // S^T = K.Q^T: A = K-frag (m=key), B = Q-frag (n=q); chain d-halves
    f32x4 st[2][NQF];  // [key-tile kt][qi]
#pragma unroll
    for (int kt = 0; kt < 2; ++kt) {
      bf16x8 ka0 = as_bf(*(const u16x8*)(&Kt[cur][kt * 16 + ln15][q8]));
      bf16x8 ka1 = as_bf(*(const u16x8*)(&Kt[cur][kt * 16 + ln15][32 + q8]));
#pragma unroll
      for (int qi = 0; qi < NQF; ++qi) {
        f32x4 z = f32x4{0.f, 0.f, 0.f, 0.f};
        z = mfma16(ka0, qf[qi][0], z);
        z = mfma16(ka1, qf[qi][1], z);
        st[kt][qi] = z;
      }
    }

    // p = exp2(s^T); assemble PV B-frag IN REGISTERS (slot j<4 = kt0 reg j, j>=4 = kt1)
    bf16x8 pb[NQF];
#pragma unroll
    for (int qi = 0; qi < NQF; ++qi) {
      float p00 = __builtin_amdgcn_exp2f(st[0][qi][0]);
      float p01 = __builtin_amdgcn_exp2f(st[0][qi][1]);
      float p02 = __builtin_amdgcn_exp2f(st[0][qi][2]);
      float p03 = __builtin_amdgcn_exp2f(st[0][qi][3]);
      float p10 = __builtin_amdgcn_exp2f(st[1][qi][0]);
      float p11 = __builtin_amdgcn_exp2f(st[1][qi][1]);
      float p12 = __builtin_amdgcn_exp2f(st[1][qi][2]);
      float p13 = __builtin_amdgcn_exp2f(st[1][qi][3]);
      u32x4 pk;
      pk[0] = cvt_pk_bf16(p00, p01);
      pk[1] = cvt_pk_bf16(p02, p03);
      pk[2] = cvt_pk_bf16(p10, p11);
      pk[3] = cvt_pk_bf16(p12, p13);
      pb[qi] = as_bf(__builtin_bit_cast(u16x8, pk));
      lacc[qi] = mfma16(onesb, pb[qi], lacc[qi]);  // l[q] in every C row
    }
    // PV: O^T[d][q]; A = V^T slot-permuted (b128), B = pb
#pragma unroll
    for (int j = 0; j < 4; ++j) {
      bf16x8 av = as_bf(*(const u16x8*)(&Vt[cur][j * 16 + ln15][q8]));
#pragma unroll
      for (int qi = 0; qi < NQF; ++qi) o[qi][j] = mfma16(av, pb[qi], o[qi][j]);
    }
    // no trailing barrier: next iter commits into buffer cur^1 (disjoint); the next
    // barrier orders reuse of THIS buffer two iters out.
  }

  // normalize + store ctx bf16: O^T C-layout col=q=ln15, row=d=j*16+quad*4+r
#pragma unroll
  for (int qi = 0; qi < NQF; ++qi) {
    float inv = outscale / lacc[qi][0];
    long row = qrow + qi * 16 + ln15;
#pragma unroll
    for (int j = 0; j < 4; ++j) {
      u16x4 ov;
#pragma unroll
      for (int r = 0; r < 4; ++r) ov[r] = f2bf(o[qi][j][r] * inv);
      *(u16x4*)(O + row * ldo + h * 64 + j * 16 + quad * 4) = ov;
    }
  }
}

extern "C" void kernel_launch(void* const* d_in, const int* in_sizes, int n_in,
                              void* d_out, int out_size, void* d_ws, size_t ws_size,
                              hipStream_t stream) {
  const float* hidden = (const float*)d_in[0];
  const float* text   = (const float*)d_in[1];
  const float* wqi = (const float*)d_in[2];  const float* bqi = (const float*)d_in[3];
  const float* wki = (const float*)d_in[4];  const float* bki = (const float*)d_in[5];
  const float* wvi = (const float*)d_in[6];  const float* bvi = (const float*)d_in[7];
  const float* wqt = (const float*)d_in[8];  const float* bqt = (const float*)d_in[9];
  const float* wkt = (const float*)d_in[10]; const float* bkt = (const float*)d_in[11];
  const float* wvt = (const float*)d_in[12]; const float* bvt = (const float*)d_in[13];
  const float* woi = (const float*)d_in[14]; const float* boi = (const float*)d_in[15];
  const float* wot = (const float*)d_in[16]; const float* bot = (const float*)d_in[17];
  const float* wc  = (const float*)d_in[18]; const float* bc  = (const float*)d_in[19];
  const float* wip = (const float*)d_in[20]; const float* bip = (const float*)d_in[21];
  const float* wop = (const float*)d_in[22]; const float* bop = (const float*)d_in[23];

  char* ws = (char*)d_ws;
  u16* WB    = (u16*)(ws + WS_W);
  float* BQI = (float*)(ws + WS_BQI);
  float* BQT = (float*)(ws + WS_BQT);
  u16* QKVI  = (u16*)(ws + WS_QKVI);
  u16* QKVT  = (u16*)(ws + WS_QKVT);
  u16* VTI   = (u16*)(ws + WS_VTI);
  u16* VTT   = (u16*)(ws + WS_VTT);
  u16* CTXIA = (u16*)(ws + WS_CTXIA);
  u16* CTXIB = (u16*)(ws + WS_XH);
  u16* CTXTA = (u16*)(ws + WS_CTXTA);
  u16* CTXTB = (u16*)(ws + WS_XT);
  u16* OCAT  = (u16*)(ws + WS_OCAT);
  u16* OUT2  = (u16*)(ws + WS_OUT2);
  u16* QKVP  = (u16*)(ws + WS_QKVP);
  u16* VTP   = (u16*)(ws + WS_VTP);
  u16* CTXP  = (u16*)(ws + WS_CTXP);

  u16* WQKVI = WB;                 // [1536][512]
  u16* WOUTI = WB + 1572864;
  u16* WCAT  = WB + 2097152;
  u16* WINP  = WB + 2621440;
  u16* WOUTP = WB + 3407872;

  // byte-delta/2 between the two independent fp32 activation buffers (flat addr space)
  long zdA_ht = ((const char*)text - (const char*)hidden) / 2;

  // 1. convert weights + concat biases
  prep_weights<<<dim3(14348), 256, 0, stream>>>(wqi, wki, wvi, wqt, wkt, wvt, woi, wot,
                                                wc, wip, wop, bqi, bki, bvi, bqt, bkt, bvt,
                                                WB, BQI, BQT);
  // 2. fused QKV GEMMs, img+txt merged via z; A read DIRECTLY from fp32 activations
  gemm_bf16<<<dim3(64, 12, 2), 256, 0, stream>>>(
      (const u16*)hidden, nullptr, 512, /*af32=*/1, WQKVI, BQI, QKVI, 1536, 0, 512,
      0, 512, SCALE_LOG2E_O8, VTI,
      /*zdA=*/zdA_ht, 0, /*zdW=*/786432, /*zdB=*/1536, /*zdC=*/12582912, /*zdVT=*/4194304, 0);
  // 3. ALL FOUR dual attentions in one launch, NQF=2 (z = b*2 + qsel; x = qtile*2 + phase)
  attn_flash<2, true><<<dim3(16, 8, 16), 256, 0, stream>>>(
      QKVI, QKVT, 1536, QKVI + 512, VTI, QKVT + 512, VTT, 1536,
      CTXIA, CTXIB, CTXTA, CTXTB, 512, 0.5f);
  // 4. out projections (A + A2 merge), img+txt merged via z-deltas -> concat buffer
  gemm_bf16<<<dim3(64, 4, 2), 256, 0, stream>>>(
      CTXIA, CTXIB, 512, 0, WOUTI, boi, OCAT, 1024, 0, 512, 0, 0, 1.0f, nullptr,
      /*zdA=*/4194304, /*zdA2=*/4194304, /*zdW=*/262144, /*zdB=*/(long)(bot - boi),
      /*zdC=*/0, 0, /*zdCoff=*/512);
  // 5. cat GEMM (K=1024)
  gemm_bf16<<<dim3(64, 4, 1), 256, 0, stream>>>(
      OCAT, nullptr, 1024, 0, WCAT, bc, OUT2, 512, 0, 1024, 0, 0, 1.0f, nullptr,
      0, 0, 0, 0, 0, 0, 0);
  // 6. pooled in_proj (Q cols pre-scaled; V -> VTP via epilogue)
  gemm_bf16<<<dim3(64, 12, 1), 256, 0, stream>>>(
      OUT2, nullptr, 512, 0, WINP, bip, QKVP, 1536, 0, 512, 0, 512, SCALE_LOG2E_O8, VTP,
      0, 0, 0, 0, 0, 0, 0);
  // 7. pooled attention (single, NQF=2, 8 qtiles)
  attn_flash<2, false><<<dim3(8, 8, 8), 256, 0, stream>>>(
      QKVP, nullptr, 1536, QKVP + 512, VTP, nullptr, nullptr, 1536,
      CTXP, nullptr, nullptr, nullptr, 512, 1.0f);
  // 8. final out_proj -> d_out (FP32! reference output dtype is float32)
  gemm_bf16<<<dim3(64, 4, 1), 256, 0, stream>>>(
      CTXP, nullptr, 512, 0, WOUTP, bop, (u16*)d_out, 512, 0, 512, 1, 0, 1.0f, nullptr,
      0, 0, 0, 0, 0, 0, 0);
}

// Round 8
// 381.425 us; speedup vs baseline: 1.0672x; 1.0672x over previous
//
#include <hip/hip_runtime.h>

typedef unsigned short u16;
typedef __attribute__((ext_vector_type(4))) unsigned short u16x4;
typedef __attribute__((ext_vector_type(8))) unsigned short u16x8;
typedef __attribute__((ext_vector_type(4))) float f32x4;
typedef __attribute__((ext_vector_type(8))) __bf16 bf16x8;
typedef __attribute__((ext_vector_type(2))) unsigned int u32x2;
typedef __attribute__((ext_vector_type(4))) unsigned int u32x4;

// ---- workspace layout (bytes) ----
#define WS_XH    0UL          // hidden bf16 [8192][512]; dead after QKV GEMMs -> reused as CTXIB
#define WS_XT    8388608UL    // text bf16; dead after QKV GEMMs -> reused as CTXTB
#define WS_W     16777216UL   // all weights bf16, contiguous (see prep_weights)
#define WS_BQI   24117248UL   // concat bias qkv_img fp32 [1536]
#define WS_BQT   24123392UL   // concat bias qkv_txt fp32 [1536]
#define WS_QKVI  24129536UL   // qkv_img bf16 [8192][1536] (V cols never written; Q pre-scaled)
#define WS_QKVT  49295360UL   // qkv_txt bf16
#define WS_VTI   74461184UL   // v_img^T bf16 [8*8*64][1024]  (written by GEMM epilogue)
#define WS_VTT   82849792UL   // v_txt^T
#define WS_CTXIA 91238400UL   // ctx img, img-key phase, bf16 [8192][512] (*0.5)
#define WS_CTXTA 99627008UL   // ctx txt, txt-key phase
#define WS_OCAT  108015616UL  // concat out bf16 [8192][1024]
// reuse of QKV_I/QKV_T region after attentions complete:
#define WS_OUT2  24129536UL   // out after w_cat bf16 [8192][512]
#define WS_QKVP  32518144UL   // pooled qkv bf16 [8192][1536]
#define WS_VTP   57683968UL   // v_pool^T
#define WS_CTXP  66072576UL   // ctx_pool bf16 [8192][512]

#define SCALE_LOG2E_O8 0.18033688011112042f  // log2(e)/8

// ===== Session ledger (measured deltas vs R2-best 390.4 us) =====
//  gl_lds GEMM staging      ~ +5   (R3)   -> reg staging kept
//  dual attn NQF=4          ~ +5   (R4)   -> NQF=2 kept (issue-saturated point)
//  pooled attn NQF=2        ~ -5   (R4/R6 differencing) -> kept
//  R5 outproj+cat+inproj fusion  +74    -> reverted (latency-bound fused GEMM + prep chain)
//  af32 (fp32 A direct)     ~ +14  (R6)   -> reverted (doubles A re-read traffic in L2/L3)
//  2-deep pipeline + raw barrier ~ +8 (R7) -> reverted (VGPR 100, occ 19%)
// GEMM staging variants are exhausted: structure sits on the m102 skinny-K curve (~300 TF).

__device__ __forceinline__ u16 f2bf(float f) {
  unsigned u = __float_as_uint(f);
  u += 0x7fffu + ((u >> 16) & 1u);   // RNE
  return (u16)(u >> 16);
}
__device__ __forceinline__ float bf2f(u16 v) {
  return __uint_as_float(((unsigned)v) << 16);
}
__device__ __forceinline__ bf16x8 as_bf(u16x8 v) { return __builtin_bit_cast(bf16x8, v); }
__device__ __forceinline__ f32x4 mfma16(bf16x8 a, bf16x8 b, f32x4 c) {
  return __builtin_amdgcn_mfma_f32_16x16x32_bf16(a, b, c, 0, 0, 0);
}
// pack two fp32 into one u32 of 2x bf16 in ONE VALU op (RNE)
__device__ __forceinline__ unsigned cvt_pk_bf16(float lo, float hi) {
  unsigned r;
  asm("v_cvt_pk_bf16_f32 %0, %1, %2" : "=v"(r) : "v"(lo), "v"(hi));
  return r;
}

// ---------------- fp32 -> bf16 activation convert (both tensors, one launch) ----------------
__global__ __launch_bounds__(256) void cvt_f32_bf16(const float* __restrict__ s0,
                                                    const float* __restrict__ s1,
                                                    u16* __restrict__ d0,
                                                    u16* __restrict__ d1, int n) {
  const float* s = blockIdx.y ? s1 : s0;
  u16* d = blockIdx.y ? d1 : d0;
  int i = (blockIdx.x * 256 + threadIdx.x) * 4;
  if (i >= n) return;
  float4 v = *(const float4*)(s + i);
  u16x4 o;
  o[0] = f2bf(v.x); o[1] = f2bf(v.y); o[2] = f2bf(v.z); o[3] = f2bf(v.w);
  *(u16x4*)(d + i) = o;
}

// ---------------- weight prep: convert+concat all weights / biases ----------------
__global__ __launch_bounds__(256) void prep_weights(
    const float* __restrict__ wqi, const float* __restrict__ wki, const float* __restrict__ wvi,
    const float* __restrict__ wqt, const float* __restrict__ wkt, const float* __restrict__ wvt,
    const float* __restrict__ woi, const float* __restrict__ wot,
    const float* __restrict__ wc,  const float* __restrict__ wip, const float* __restrict__ wop,
    const float* __restrict__ bqi, const float* __restrict__ bki, const float* __restrict__ bvi,
    const float* __restrict__ bqt, const float* __restrict__ bkt, const float* __restrict__ bvt,
    u16* __restrict__ wdst, float* __restrict__ bi, float* __restrict__ bt) {
  int i = blockIdx.x * 256 + threadIdx.x;
  if (i < 786432) {
    const float* s = i < 262144 ? wqi : (i < 524288 ? wki : wvi);
    wdst[i] = f2bf(s[i & 262143]);
  } else if (i < 1572864) {
    int j = i - 786432;
    const float* s = j < 262144 ? wqt : (j < 524288 ? wkt : wvt);
    wdst[i] = f2bf(s[j & 262143]);
  } else if (i < 1835008) wdst[i] = f2bf(woi[i - 1572864]);
  else if (i < 2097152)   wdst[i] = f2bf(wot[i - 1835008]);
  else if (i < 2621440)   wdst[i] = f2bf(wc [i - 2097152]);
  else if (i < 3407872)   wdst[i] = f2bf(wip[i - 2621440]);
  else if (i < 3670016)   wdst[i] = f2bf(wop[i - 3407872]);
  else if (i < 3671552) {
    int j = i - 3670016;
    bi[j] = j < 512 ? bqi[j] : (j < 1024 ? bki[j - 512] : bvi[j - 1024]);
  } else if (i < 3673088) {
    int j = i - 3671552;
    bt[j] = j < 512 ? bqt[j] : (j < 1024 ? bkt[j - 512] : bvt[j - 1024]);
  }
}

// ---------------- GEMM: C[M,N] = (A [+ A2])[M,K](bf16) @ W[N,K]^T + bias(f32) ----------------
// 128x128 tile, 4 waves (2x2 of 64x64), BK=32. Register staging + double-buffered LDS,
// one barrier per K-iter; prefetch issued AFTER the barrier. R2-measured-best structure
// (390.4 us total); every staging variant since measured worse (see ledger above).
__global__ __launch_bounds__(256) void gemm_bf16(
    const u16* __restrict__ A, const u16* __restrict__ A2, int lda,
    const u16* __restrict__ W,
    const float* __restrict__ bias, u16* __restrict__ C, int ldc, int coff, int K,
    int f32out, int qcols, float qscale, u16* __restrict__ vtout,
    long zdA, long zdA2, long zdW, long zdB, long zdC, long zdVT, int zdCoff) {
  if (blockIdx.z) {
    A += zdA;
    if (A2) A2 += zdA2;
    W += zdW; bias += zdB; C += zdC;
    if (vtout) vtout += zdVT;
    coff += zdCoff;
  }
  __shared__ __align__(16) u16 As[2][8 * 512];   // 8 KB per buffer
  __shared__ __align__(16) u16 Bs[2][8 * 512];
  const int tid = threadIdx.x, lane = tid & 63, wv = tid >> 6;
  const int wm = wv >> 1, wn = wv & 1;
  const int ln15 = lane & 15;
  const int m0 = blockIdx.x * 128, n0 = blockIdx.y * 128;

  // staging maps: wave wv stages A rows [wv*32,+32) and W rows likewise (2 16-row blocks each)
  const int srow = lane & 15, skc = lane >> 4;
  const u16* gA0 = A + (long)(m0 + wv * 32 + srow) * lda + skc * 8;
  const u16* gA1 = gA0 + (long)16 * lda;
  const u16* gW0 = W + (long)(n0 + wv * 32 + srow) * K + skc * 8;
  const u16* gW1 = gW0 + (long)16 * K;
  const u16* gA20 = A2 + (long)(m0 + wv * 32 + srow) * lda + skc * 8;  // valid only if A2
  const u16* gA21 = gA20 + (long)16 * lda;

  f32x4 acc[4][4];
#pragma unroll
  for (int j = 0; j < 4; ++j) {
    float bv = bias[n0 + wn * 64 + j * 16 + ln15];
#pragma unroll
    for (int i = 0; i < 4; ++i) acc[i][j] = f32x4{bv, bv, bv, bv};
  }

  // prologue: load tile 0 into registers
  u16x8 ra0 = *(const u16x8*)(gA0);
  u16x8 ra1 = *(const u16x8*)(gA1);
  u16x8 rb0 = *(const u16x8*)(gW0);
  u16x8 rb1 = *(const u16x8*)(gW1);
  u16x8 rc0, rc1;
  if (A2) { rc0 = *(const u16x8*)(gA20); rc1 = *(const u16x8*)(gA21); }

  int buf = 0;
  for (int k0 = 0; k0 < K; k0 += 32, buf ^= 1) {
    u16x8 wa0 = ra0, wa1 = ra1;
    if (A2) {
#pragma unroll
      for (int u = 0; u < 8; ++u) {
        wa0[u] = f2bf(bf2f(ra0[u]) + bf2f(rc0[u]));
        wa1[u] = f2bf(bf2f(ra1[u]) + bf2f(rc1[u]));
      }
    }
    u16* la = As[buf] + (wv * 2) * 512;
    u16* lb = Bs[buf] + (wv * 2) * 512;
    *(u16x8*)(la + lane * 8) = wa0;
    *(u16x8*)(la + 512 + lane * 8) = wa1;
    *(u16x8*)(lb + lane * 8) = rb0;
    *(u16x8*)(lb + 512 + lane * 8) = rb1;
    __syncthreads();
    // prefetch next tile AFTER the barrier (barrier would drain vmcnt otherwise)
    if (k0 + 32 < K) {
      ra0 = *(const u16x8*)(gA0 + k0 + 32);
      ra1 = *(const u16x8*)(gA1 + k0 + 32);
      rb0 = *(const u16x8*)(gW0 + k0 + 32);
      rb1 = *(const u16x8*)(gW1 + k0 + 32);
      if (A2) { rc0 = *(const u16x8*)(gA20 + k0 + 32); rc1 = *(const u16x8*)(gA21 + k0 + 32); }
    }

    bf16x8 af[4], bfr[4];
#pragma unroll
    for (int i = 0; i < 4; ++i)
      af[i] = as_bf(*(const u16x8*)(As[buf] + (wm * 4 + i) * 512 + lane * 8));
#pragma unroll
    for (int j = 0; j < 4; ++j)
      bfr[j] = as_bf(*(const u16x8*)(Bs[buf] + (wn * 4 + j) * 512 + lane * 8));
#pragma unroll
    for (int i = 0; i < 4; ++i)
#pragma unroll
      for (int j = 0; j < 4; ++j) acc[i][j] = mfma16(af[i], bfr[j], acc[i][j]);
  }
  // epilogue: C/D layout col=lane&15, row=quad*4+reg (m89/m91 verified)
  const int quad = lane >> 4;
  const int qr4 = quad * 4;
  if (vtout && n0 >= 1024) {
    // V tile -> transposed store into VT[(b*8+h)*64+d][l]
#pragma unroll
    for (int j = 0; j < 4; ++j) {
      int col = n0 + wn * 64 + j * 16 + ln15;    // 1024..1535
      int dg = col - 1024;
#pragma unroll
      for (int i = 0; i < 4; ++i) {
        int row0 = m0 + wm * 64 + i * 16 + qr4;  // 4 consecutive C-rows = 4 VT cols
        long vr = ((long)(row0 >> 10) * 8 + (dg >> 6)) * 64 + (dg & 63);
        u16x4 ov;
#pragma unroll
        for (int r = 0; r < 4; ++r) ov[r] = f2bf(acc[i][j][r]);
        *(u16x4*)(vtout + vr * 1024 + (row0 & 1023)) = ov;
      }
    }
    return;
  }
  float colsc[4];
#pragma unroll
  for (int j = 0; j < 4; ++j)
    colsc[j] = (n0 + wn * 64 + j * 16 < qcols) ? qscale : 1.0f;
#pragma unroll
  for (int i = 0; i < 4; ++i)
#pragma unroll
    for (int r = 0; r < 4; ++r) {
      int row = m0 + wm * 64 + i * 16 + qr4 + r;
      long cidx = (long)row * ldc + coff + n0 + wn * 64 + ln15;
      if (f32out) {
        float* cf = (float*)C + cidx;
#pragma unroll
        for (int j = 0; j < 4; ++j) cf[j * 16] = acc[i][j][r] * colsc[j];
      } else {
        u16* cp = C + cidx;
#pragma unroll
        for (int j = 0; j < 4; ++j) cp[j * 16] = f2bf(acc[i][j][r] * colsc[j]);
      }
    }
}

// ---------------- flash attention, S^T formulation: NO P LDS round-trip ----------------
// Compute S^T = K.Q^T (A=K-frag from Kt, B=Q-frag). S^T C-layout IS a PV B-fragment under
// the fixed key permutation slot(quad*8+j) <-> key (j<4 ? 4q+j : 16+4q+j-4): P packs
// entirely in registers. l = ones.P^T via 1 MFMA. No-max softmax (Q pre-scaled by log2e/8).
//
// R8: T5 s_setprio(1) wrapped around the two MFMA clusters (S^T chain, PV loop). Catalog
// m191: +4-7% on attn structures with blocks at independent loop phases (ours: merged
// 2048-block launch, no inter-block sync); null on barrier-locked GEMM (m190) so GEMM
// is untouched. NQF=2 is the measured sweet spot (R4). __launch_bounds__ stays (256)
// with NO min-waves clause ((256,8) caps VGPR at 64 -> scratch spill, 19x slower, R1).
template <int NQF, bool DUAL>
__global__ __launch_bounds__(256) void attn_flash(
    const u16* __restrict__ Q0, const u16* __restrict__ Q1, int ldq,
    const u16* __restrict__ K0, const u16* __restrict__ VT0,
    const u16* __restrict__ K1, const u16* __restrict__ VT1, int ldk,
    u16* __restrict__ O00, u16* __restrict__ O01,
    u16* __restrict__ O10, u16* __restrict__ O11, int ldo, float outscale) {
  __shared__ __align__(16) u16 Kt[2][32][72];   // K tile, natural key order [key][d]
  __shared__ __align__(16) u16 Vt[2][64][40];   // V^T tile, slot-permuted key order [d][slot]
  const int tid = threadIdx.x, lane = tid & 63, wv = tid >> 6;
  const int ln15 = lane & 15, quad = lane >> 4, q8 = quad * 8;
  const int h = blockIdx.y;

  const u16 *Q, *K, *VT;
  u16* O;
  int qtile, b;
  if constexpr (DUAL) {
    qtile = blockIdx.x >> 1;
    const int phase = blockIdx.x & 1;
    const int qsel = blockIdx.z & 1;
    b = blockIdx.z >> 1;
    Q = qsel ? Q1 : Q0;
    const int ksel = qsel ^ phase;   // 0: img keys, 1: txt keys
    K = ksel ? K1 : K0;
    VT = ksel ? VT1 : VT0;
    O = qsel ? (phase ? O11 : O10) : (phase ? O01 : O00);
  } else {
    qtile = blockIdx.x;
    b = blockIdx.z;
    Q = Q0; K = K0; VT = VT0; O = O00;
  }
  const long qrow = (long)b * 1024 + qtile * (NQF * 64) + wv * (NQF * 16);

  // Q fragments (serve as MFMA B operand: n=lane&15=q, k=quad*8+j=d) [qi][d-half]
  bf16x8 qf[NQF][2];
#pragma unroll
  for (int qi = 0; qi < NQF; ++qi) {
    const u16* qp = Q + (qrow + qi * 16 + ln15) * ldq + h * 64;
    qf[qi][0] = as_bf(*(const u16x8*)(qp + q8));
    qf[qi][1] = as_bf(*(const u16x8*)(qp + 32 + q8));
  }

  u16x8 ones_u;
#pragma unroll
  for (int j = 0; j < 8; ++j) ones_u[j] = 0x3F80;  // bf16 1.0
  const bf16x8 onesb = as_bf(ones_u);

  // staging thread->element maps
  const int kk = tid >> 3, dc = (tid & 7) * 8;        // K: natural rows
  const int vd = tid >> 2;                            // V: d-row
  const int ko = (tid & 3) * 8;                       // natural key offset (8 keys)
  const int vs0 = ((tid & 1) << 4) | ((tid & 2) << 1);// slot base: ko 0,8,16,24 -> 0,16,4,20
  const u16* Kbase = K + ((long)b * 1024 + kk) * ldk + h * 64 + dc;
  const u16* Vbase = VT + ((long)((b * 8 + h) * 64 + vd)) * 1024 + ko;

  f32x4 o[NQF][4];
  f32x4 lacc[NQF];
#pragma unroll
  for (int qi = 0; qi < NQF; ++qi) {
    lacc[qi] = f32x4{0.f, 0.f, 0.f, 0.f};
#pragma unroll
    for (int j = 0; j < 4; ++j) o[qi][j] = f32x4{0.f, 0.f, 0.f, 0.f};
  }

  // prefetch tile 0
  u32x4 kreg = *(const u32x4*)(Kbase);
  u32x4 vreg = *(const u32x4*)(Vbase);

  int cur = 0;
  for (int k0 = 0; k0 < 1024; k0 += 32, cur ^= 1) {
    // commit staged regs for THIS tile into buffer cur (waits the in-flight loads here)
    *(u32x4*)(&Kt[cur][kk][dc]) = kreg;
    u32x2 vlo = {vreg[0], vreg[1]}, vhi = {vreg[2], vreg[3]};
    *(u32x2*)(&Vt[cur][vd][vs0]) = vlo;
    *(u32x2*)(&Vt[cur][vd][vs0 + 8]) = vhi;
    __syncthreads();
    // issue next tile's global loads AFTER the barrier (so its vmcnt(0) doesn't drain them)
    if (k0 + 32 < 1024) {
      kreg = *(const u32x4*)(Kbase + (long)(k0 + 32) * ldk);
      vreg = *(const u32x4*)(Vbase + (k0 + 32));
    }

    // S^T = K.Q^T: A = K-frag (m=key), B = Q-frag (n=q); chain d-halves
    f32x4 st[2][NQF];  // [key-tile kt][qi]
    __builtin_amdgcn_s_setprio(1);   // T5: favor this wave's MFMA cluster
#pragma unroll
    for (int kt = 0; kt < 2; ++kt) {
      bf16x8 ka0 = as_bf(*(const u16x8*)(&Kt[cur][kt * 16 + ln15][q8]));
      bf16x8 ka1 = as_bf(*(const u16x8*)(&Kt[cur][kt * 16 + ln15][32 + q8]));
#pragma unroll
      for (int qi = 0; qi < NQF; ++qi) {
        f32x4 z = f32x4{0.f, 0.f, 0.f, 0.f};
        z = mfma16(ka0, qf[qi][0], z);
        z = mfma16(ka1, qf[qi][1], z);
        st[kt][qi] = z;
      }
    }
    __builtin_amdgcn_s_setprio(0);

    // p = exp2(s^T); assemble PV B-frag IN REGISTERS (slot j<4 = kt0 reg j, j>=4 = kt1)
    bf16x8 pb[NQF];
#pragma unroll
    for (int qi = 0; qi < NQF; ++qi) {
      float p00 = __builtin_amdgcn_exp2f(st[0][qi][0]);
      float p01 = __builtin_amdgcn_exp2f(st[0][qi][1]);
      float p02 = __builtin_amdgcn_exp2f(st[0][qi][2]);
      float p03 = __builtin_amdgcn_exp2f(st[0][qi][3]);
      float p10 = __builtin_amdgcn_exp2f(st[1][qi][0]);
      float p11 = __builtin_amdgcn_exp2f(st[1][qi][1]);
      float p12 = __builtin_amdgcn_exp2f(st[1][qi][2]);
      float p13 = __builtin_amdgcn_exp2f(st[1][qi][3]);
      u32x4 pk;
      pk[0] = cvt_pk_bf16(p00, p01);
      pk[1] = cvt_pk_bf16(p02, p03);
      pk[2] = cvt_pk_bf16(p10, p11);
      pk[3] = cvt_pk_bf16(p12, p13);
      pb[qi] = as_bf(__builtin_bit_cast(u16x8, pk));
      lacc[qi] = mfma16(onesb, pb[qi], lacc[qi]);  // l[q] in every C row
    }
    // PV: O^T[d][q]; A = V^T slot-permuted (b128), B = pb
    __builtin_amdgcn_s_setprio(1);   // T5: PV MFMA cluster
#pragma unroll
    for (int j = 0; j < 4; ++j) {
      bf16x8 av = as_bf(*(const u16x8*)(&Vt[cur][j * 16 + ln15][q8]));
#pragma unroll
      for (int qi = 0; qi < NQF; ++qi) o[qi][j] = mfma16(av, pb[qi], o[qi][j]);
    }
    __builtin_amdgcn_s_setprio(0);
    // no trailing barrier: next iter commits into buffer cur^1 (disjoint); the next
    // barrier orders reuse of THIS buffer two iters out.
  }

  // normalize + store ctx bf16: O^T C-layout col=q=ln15, row=d=j*16+quad*4+r
#pragma unroll
  for (int qi = 0; qi < NQF; ++qi) {
    float inv = outscale / lacc[qi][0];
    long row = qrow + qi * 16 + ln15;
#pragma unroll
    for (int j = 0; j < 4; ++j) {
      u16x4 ov;
#pragma unroll
      for (int r = 0; r < 4; ++r) ov[r] = f2bf(o[qi][j][r] * inv);
      *(u16x4*)(O + row * ldo + h * 64 + j * 16 + quad * 4) = ov;
    }
  }
}

extern "C" void kernel_launch(void* const* d_in, const int* in_sizes, int n_in,
                              void* d_out, int out_size, void* d_ws, size_t ws_size,
                              hipStream_t stream) {
  const float* hidden = (const float*)d_in[0];
  const float* text   = (const float*)d_in[1];
  const float* wqi = (const float*)d_in[2];  const float* bqi = (const float*)d_in[3];
  const float* wki = (const float*)d_in[4];  const float* bki = (const float*)d_in[5];
  const float* wvi = (const float*)d_in[6];  const float* bvi = (const float*)d_in[7];
  const float* wqt = (const float*)d_in[8];  const float* bqt = (const float*)d_in[9];
  const float* wkt = (const float*)d_in[10]; const float* bkt = (const float*)d_in[11];
  const float* wvt = (const float*)d_in[12]; const float* bvt = (const float*)d_in[13];
  const float* woi = (const float*)d_in[14]; const float* boi = (const float*)d_in[15];
  const float* wot = (const float*)d_in[16]; const float* bot = (const float*)d_in[17];
  const float* wc  = (const float*)d_in[18]; const float* bc  = (const float*)d_in[19];
  const float* wip = (const float*)d_in[20]; const float* bip = (const float*)d_in[21];
  const float* wop = (const float*)d_in[22]; const float* bop = (const float*)d_in[23];

  char* ws = (char*)d_ws;
  u16* XH    = (u16*)(ws + WS_XH);
  u16* XT    = (u16*)(ws + WS_XT);
  u16* WB    = (u16*)(ws + WS_W);
  float* BQI = (float*)(ws + WS_BQI);
  float* BQT = (float*)(ws + WS_BQT);
  u16* QKVI  = (u16*)(ws + WS_QKVI);
  u16* QKVT  = (u16*)(ws + WS_QKVT);
  u16* VTI   = (u16*)(ws + WS_VTI);
  u16* VTT   = (u16*)(ws + WS_VTT);
  u16* CTXIA = (u16*)(ws + WS_CTXIA);
  u16* CTXIB = (u16*)(ws + WS_XH);    // XH dead after QKV GEMMs
  u16* CTXTA = (u16*)(ws + WS_CTXTA);
  u16* CTXTB = (u16*)(ws + WS_XT);    // XT dead after QKV GEMMs
  u16* OCAT  = (u16*)(ws + WS_OCAT);
  u16* OUT2  = (u16*)(ws + WS_OUT2);
  u16* QKVP  = (u16*)(ws + WS_QKVP);
  u16* VTP   = (u16*)(ws + WS_VTP);
  u16* CTXP  = (u16*)(ws + WS_CTXP);

  u16* WQKVI = WB;                 // [1536][512]
  u16* WOUTI = WB + 1572864;
  u16* WCAT  = WB + 2097152;
  u16* WINP  = WB + 2621440;
  u16* WOUTP = WB + 3407872;

  const int NACT = 8192 * 512;

  // 1. convert activations (merged) + weights
  cvt_f32_bf16<<<dim3(NACT / 1024, 2), 256, 0, stream>>>(hidden, text, XH, XT, NACT);
  prep_weights<<<dim3(14348), 256, 0, stream>>>(wqi, wki, wvi, wqt, wkt, wvt, woi, wot,
                                                wc, wip, wop, bqi, bki, bvi, bqt, bkt, bvt,
                                                WB, BQI, BQT);
  // 2. fused QKV GEMMs, img+txt merged into one launch via z-deltas
  //    (Q cols pre-scaled; V tiles written transposed to VT by epilogue)
  gemm_bf16<<<dim3(64, 12, 2), 256, 0, stream>>>(
      XH, nullptr, 512, WQKVI, BQI, QKVI, 1536, 0, 512, 0, 512, SCALE_LOG2E_O8, VTI,
      /*zdA=*/4194304, 0, /*zdW=*/786432, /*zdB=*/1536, /*zdC=*/12582912, /*zdVT=*/4194304, 0);
  // 3. ALL FOUR dual attentions in one launch, NQF=2 (z = b*2 + qsel; x = qtile*2 + phase)
  attn_flash<2, true><<<dim3(16, 8, 16), 256, 0, stream>>>(
      QKVI, QKVT, 1536, QKVI + 512, VTI, QKVT + 512, VTT, 1536,
      CTXIA, CTXIB, CTXTA, CTXTB, 512, 0.5f);
  // 4. out projections (A + A2 merge), img+txt merged via z-deltas -> concat buffer
  gemm_bf16<<<dim3(64, 4, 2), 256, 0, stream>>>(
      CTXIA, CTXIB, 512, WOUTI, boi, OCAT, 1024, 0, 512, 0, 0, 1.0f, nullptr,
      /*zdA=*/4194304, /*zdA2=*/4194304, /*zdW=*/262144, /*zdB=*/(long)(bot - boi),
      /*zdC=*/0, 0, /*zdCoff=*/512);
  // 5. cat GEMM (K=1024)
  gemm_bf16<<<dim3(64, 4, 1), 256, 0, stream>>>(
      OCAT, nullptr, 1024, WCAT, bc, OUT2, 512, 0, 1024, 0, 0, 1.0f, nullptr,
      0, 0, 0, 0, 0, 0, 0);
  // 6. pooled in_proj (Q cols pre-scaled; V -> VTP via epilogue)
  gemm_bf16<<<dim3(64, 12, 1), 256, 0, stream>>>(
      OUT2, nullptr, 512, WINP, bip, QKVP, 1536, 0, 512, 0, 512, SCALE_LOG2E_O8, VTP,
      0, 0, 0, 0, 0, 0, 0);
  // 7. pooled attention (single, NQF=2, 8 qtiles)
  attn_flash<2, false><<<dim3(8, 8, 8), 256, 0, stream>>>(
      QKVP, nullptr, 1536, QKVP + 512, VTP, nullptr, nullptr, 1536,
      CTXP, nullptr, nullptr, nullptr, 512, 1.0f);
  // 8. final out_proj -> d_out (FP32! reference output dtype is float32)
  gemm_bf16<<<dim3(64, 4, 1), 256, 0, stream>>>(
      CTXP, nullptr, 512, WOUTP, bop, (u16*)d_out, 512, 0, 512, 1, 0, 1.0f, nullptr,
      0, 0, 0, 0, 0, 0, 0);
}